// Round 1
// baseline (1035.451 us; speedup 1.0000x reference)
//
#include <hip/hip_runtime.h>
#include <stdint.h>

#define N_ROWS 262144
#define D_OUTC 128
#define M_MOD  64
#define T_CTX  16

// ---- workspace layout (bytes) ----
// Zb  : [N][64] bf16   @ 0          33,554,432 B
// SS  : [16][64][64]f32 @ ZB_BYTES     262,144 B   (unnormalized sum w*z*z)
// B   : [16][64] f32                     4,096 B   (sum w*z)
// wsum: [16] f32                            64 B
#define ZB_OFF   ((size_t)0)
#define ZB_BYTES ((size_t)N_ROWS * M_MOD * 2)
#define SS_OFF   (ZB_OFF + ZB_BYTES)
#define SS_BYTES ((size_t)T_CTX * M_MOD * M_MOD * 4)
#define B_OFF    (SS_OFF + SS_BYTES)
#define B_BYTES  ((size_t)T_CTX * M_MOD * 4)
#define WS_OFF   (B_OFF + B_BYTES)
#define WS_BYTES ((size_t)T_CTX * 4)

__device__ __forceinline__ float bf2f(unsigned short u) {
  return __uint_as_float(((unsigned int)u) << 16);
}
__device__ __forceinline__ unsigned short f2bf(float f) {
  unsigned int x = __float_as_uint(f);
  return (unsigned short)((x + 0x7fffu + ((x >> 16) & 1u)) >> 16);  // RNE
}

// ---------------- Z = Y @ Mp^T, stored bf16 ----------------
// 512 thr, 64 rows/block. lane = row-in-tile, wave -> 8 m's.
// Mp addresses are wave-uniform (readfirstlane) -> want s_load + SGPR-operand fmac.
__global__ __launch_bounds__(512) void zk_kernel(
    const float* __restrict__ Y, const float* __restrict__ Mp,
    unsigned short* __restrict__ Zb)
{
  __shared__ float Ylds[64][132];  // pad 132: breaks the stride-128 bank alias
  const int tid  = threadIdx.x;
  const int lane = tid & 63;
  const int wave = tid >> 6;
  const size_t ybase = (size_t)blockIdx.x * 64 * D_OUTC;
  const float4* Yg = (const float4*)(Y + ybase);
#pragma unroll
  for (int i = 0; i < 4; ++i) {
    int f4  = i * 512 + tid;      // 0..2047
    int row = f4 >> 5;            // 32 float4 per row
    int kq  = f4 & 31;
    float4 v = Yg[f4];
    *(float4*)&Ylds[row][kq * 4] = v;   // row*528B + kq*16B : 16B aligned
  }
  __syncthreads();
  const int m0 = __builtin_amdgcn_readfirstlane(wave * 8);
  float acc[8];
#pragma unroll
  for (int j = 0; j < 8; ++j) acc[j] = 0.f;
  for (int kc = 0; kc < 16; ++kc) {
    const int k0 = kc * 8;
    float4 y0 = *(const float4*)&Ylds[lane][k0];
    float4 y1 = *(const float4*)&Ylds[lane][k0 + 4];
    float y[8] = {y0.x, y0.y, y0.z, y0.w, y1.x, y1.y, y1.z, y1.w};
#pragma unroll
    for (int j = 0; j < 8; ++j) {
      const float* __restrict__ mr = Mp + (size_t)(m0 + j) * D_OUTC + k0;
#pragma unroll
      for (int kk = 0; kk < 8; ++kk)
        acc[j] = fmaf(y[kk], mr[kk], acc[j]);
    }
  }
  unsigned int pk[4];
#pragma unroll
  for (int j = 0; j < 4; ++j)
    pk[j] = (unsigned int)f2bf(acc[2 * j]) | ((unsigned int)f2bf(acc[2 * j + 1]) << 16);
  const size_t row = (size_t)blockIdx.x * 64 + lane;
  *(uint4*)(Zb + row * M_MOD + m0) = make_uint4(pk[0], pk[1], pk[2], pk[3]);
}

// ---------------- wsum[t] = sum_n W[n,t] ----------------
__global__ __launch_bounds__(256) void wsum_kernel(const float* __restrict__ W,
                                                   float* __restrict__ wsum)
{
  __shared__ float sred[16];
  const int tid  = threadIdx.x;
  const int gtid = blockIdx.x * 256 + tid;
  const int nth  = gridDim.x * 256;          // 65536, multiple of 4
  const int t0   = (gtid & 3) * 4;           // invariant across the stride loop
  float a0 = 0.f, a1 = 0.f, a2 = 0.f, a3 = 0.f;
  const float4* W4 = (const float4*)W;
  for (int i = gtid; i < (N_ROWS * T_CTX / 4); i += nth) {
    float4 v = W4[i];
    a0 += v.x; a1 += v.y; a2 += v.z; a3 += v.w;
  }
  if (tid < 16) sred[tid] = 0.f;
  __syncthreads();
  atomicAdd(&sred[t0 + 0], a0);
  atomicAdd(&sred[t0 + 1], a1);
  atomicAdd(&sred[t0 + 2], a2);
  atomicAdd(&sred[t0 + 3], a3);
  __syncthreads();
  if (tid < 16) atomicAdd(&wsum[tid], sred[tid]);
}

// ---------------- B[t][m] = sum_n W[n,t] * Z[n,m] ----------------
// 256 thr, 128 rows/block; lane = m; W row via wave-uniform s_load.
__global__ __launch_bounds__(256) void b_kernel(
    const unsigned short* __restrict__ Zb, const float* __restrict__ W,
    float* __restrict__ Bm)
{
  __shared__ float red[4][16][64];
  const int tid  = threadIdx.x;
  const int lane = tid & 63;
  const int wave = tid >> 6;
  const int rbase = blockIdx.x * 128;
  float acc[16];
#pragma unroll
  for (int t = 0; t < 16; ++t) acc[t] = 0.f;
  for (int rr = wave; rr < 128; rr += 4) {
    const int row = __builtin_amdgcn_readfirstlane(rbase + rr);
    float z = bf2f(Zb[(size_t)row * M_MOD + lane]);
    const float* __restrict__ wr = W + (size_t)row * T_CTX;
#pragma unroll
    for (int t = 0; t < 16; ++t) acc[t] = fmaf(wr[t], z, acc[t]);
  }
#pragma unroll
  for (int t = 0; t < 16; ++t) red[wave][t][lane] = acc[t];
  __syncthreads();
  for (int o = tid; o < 1024; o += 256) {
    int t = o >> 6, m = o & 63;
    float s = red[0][t][m] + red[1][t][m] + red[2][t][m] + red[3][t][m];
    atomicAdd(&Bm[o], s);
  }
}

// ---------------- SS[t][m][k] = sum_n W[n,t] Z[n,m] Z[n,k] ----------------
// 256 blocks x 1024 thr (16 waves = 16 contexts); 1024 rows/block in 32-row tiles.
// Thread (t, mi, ki) owns an 8x8 register tile; 64 fma + 8 mul per row.
#define SS_BLOCKS 256
#define SS_ROWS   (N_ROWS / SS_BLOCKS)   // 1024
__global__ __launch_bounds__(1024, 1) void ss_kernel(
    const unsigned short* __restrict__ Zb, const float* __restrict__ W,
    float* __restrict__ SS)
{
  __shared__ float Zl[32][68];   // pad 68 (17 granules): 2-way-max patterns
  __shared__ float Wl[32][16];
  const int tid = threadIdx.x;
  const int t   = tid >> 6;          // wave id == context
  const int mi  = (tid >> 3) & 7;
  const int ki  = tid & 7;
  const int r0b = blockIdx.x * SS_ROWS;

  float2 acc[8][4];
#pragma unroll
  for (int j = 0; j < 8; ++j)
#pragma unroll
    for (int l = 0; l < 4; ++l) { acc[j][l].x = 0.f; acc[j][l].y = 0.f; }

  for (int tile = 0; tile < SS_ROWS / 32; ++tile) {
    const int r0 = r0b + tile * 32;
    __syncthreads();   // protect LDS from previous-tile readers
    {
      int row = tid >> 5;     // 0..31
      int cp  = tid & 31;     // bf16 pair index
      unsigned int u = *(const unsigned int*)(Zb + ((size_t)(r0 + row) * M_MOD + cp * 2));
      Zl[row][cp * 2]     = bf2f((unsigned short)(u & 0xffffu));
      Zl[row][cp * 2 + 1] = bf2f((unsigned short)(u >> 16));
      if (tid < 512) {
        int wrow = tid >> 4, wt = tid & 15;
        Wl[wrow][wt] = W[(size_t)(r0 + wrow) * T_CTX + wt];
      }
    }
    __syncthreads();
#pragma unroll 4
    for (int r = 0; r < 32; ++r) {
      float wv = Wl[r][t];                    // wave-uniform broadcast
      const float* zr = &Zl[r][0];
      float4 b0 = *(const float4*)&zr[ki * 8];
      float4 b1 = *(const float4*)&zr[ki * 8 + 4];
      float4 a0 = *(const float4*)&zr[mi * 8];
      float4 a1 = *(const float4*)&zr[mi * 8 + 4];
      float a[8]  = {a0.x * wv, a0.y * wv, a0.z * wv, a0.w * wv,
                     a1.x * wv, a1.y * wv, a1.z * wv, a1.w * wv};
      float bx[8] = {b0.x, b0.y, b0.z, b0.w, b1.x, b1.y, b1.z, b1.w};
#pragma unroll
      for (int j = 0; j < 8; ++j)
#pragma unroll
        for (int l = 0; l < 4; ++l) {
          acc[j][l].x = fmaf(a[j], bx[2 * l],     acc[j][l].x);
          acc[j][l].y = fmaf(a[j], bx[2 * l + 1], acc[j][l].y);
        }
    }
  }
  float* SSp = SS + (size_t)t * 4096 + (size_t)(mi * 8) * 64 + ki * 8;
#pragma unroll
  for (int j = 0; j < 8; ++j)
#pragma unroll
    for (int l = 0; l < 4; ++l) {
      atomicAdd(&SSp[j * 64 + 2 * l],     acc[j][l].x);
      atomicAdd(&SSp[j * 64 + 2 * l + 1], acc[j][l].y);
    }
}

// ---------------- finalize: Sigma, std, C_hat, loss ----------------
__global__ __launch_bounds__(1024) void fin_kernel(
    const float* __restrict__ SS, const float* __restrict__ Bm,
    const float* __restrict__ wsum, const float* __restrict__ Cp,
    const float* __restrict__ emaS, const unsigned char* __restrict__ inited,
    float* __restrict__ out)
{
  __shared__ float mu[16][64];
  __shared__ float stdl[16][64];
  __shared__ float red[16][64];
  __shared__ float wsl[16];
  const int tid = threadIdx.x;
  const int t = tid >> 6, m = tid & 63;
  if (tid < 16) wsl[tid] = wsum[tid];
  __syncthreads();
  const float ws = wsl[t];
  const float inv_ws = 1.0f / ws;
  const float mu_tm = Bm[t * 64 + m] * inv_ws;
  mu[t][m] = mu_tm;
  __syncthreads();
  // diagonal -> sigma_sq -> std
  {
    float Smm = SS[(size_t)t * 4096 + m * 64 + m] * inv_ws - mu_tm * mu_tm;
    float de  = 0.9f * emaS[(size_t)t * 4096 + m * 64 + m] + 0.1f * Smm;
    float sq  = inited[t] ? de : Smm;
    stdl[t][m] = sqrtf(sq + 1e-6f);
  }
  __syncthreads();
  const float sm = stdl[t][m];
  float acc = 0.f;
  for (int k = 0; k < 64; ++k) {
    float Sig = SS[(size_t)t * 4096 + m * 64 + k] * inv_ws - mu_tm * mu[t][k];
    float den = sm * stdl[t][k] + 1e-6f;
    float ch  = Sig / den;
    ch = fminf(1.f, fmaxf(-1.f, ch));
    float d = ch - Cp[(size_t)t * 4096 + m * 64 + k];
    acc = fmaf(d, d, acc);
  }
  red[t][m] = acc;
  __syncthreads();
  if (tid < 16) {
    float s = 0.f;
    for (int mm = 0; mm < 64; ++mm) s += red[tid][mm];
    red[tid][0] = s / wsl[tid];           // loss_t
  }
  __syncthreads();
  if (tid == 0) {
    int na = 0; float tot = 0.f;
    for (int tt = 0; tt < 16; ++tt) {
      if (wsl[tt] >= 30.0f) { na++; tot += red[tt][0]; }
    }
    out[0] = (na > 0) ? (0.1f * 1.0f * tot / (float)na) : 0.f;
  }
}

extern "C" void kernel_launch(void* const* d_in, const int* in_sizes, int n_in,
                              void* d_out, int out_size, void* d_ws, size_t ws_size,
                              hipStream_t stream) {
  (void)in_sizes; (void)n_in; (void)out_size; (void)ws_size;
  const float* Y    = (const float*)d_in[0];
  const float* W    = (const float*)d_in[1];
  const float* Mp   = (const float*)d_in[2];
  const float* Cp   = (const float*)d_in[3];
  const float* emaS = (const float*)d_in[4];
  // d_in[5] = ema_sigma_sq: unused by the forward loss
  const unsigned char* inited = (const unsigned char*)d_in[6];
  float* out = (float*)d_out;
  char* ws = (char*)d_ws;
  unsigned short* Zb = (unsigned short*)(ws + ZB_OFF);
  float* SS   = (float*)(ws + SS_OFF);
  float* Bm   = (float*)(ws + B_OFF);
  float* wsum = (float*)(ws + WS_OFF);

  hipMemsetAsync(ws + SS_OFF, 0, SS_BYTES + B_BYTES + WS_BYTES, stream);
  zk_kernel<<<N_ROWS / 64, 512, 0, stream>>>(Y, Mp, Zb);
  wsum_kernel<<<256, 256, 0, stream>>>(W, wsum);
  b_kernel<<<N_ROWS / 128, 256, 0, stream>>>(Zb, W, Bm);
  ss_kernel<<<SS_BLOCKS, 1024, 0, stream>>>(Zb, W, SS);
  fin_kernel<<<1, 1024, 0, stream>>>(SS, Bm, wsum, Cp, emaS, inited, out);
}

// Round 2
// 234.706 us; speedup vs baseline: 4.4117x; 4.4117x over previous
//
#include <hip/hip_runtime.h>
#include <stdint.h>

#define N_ROWS 262144
#define D_OUTC 128
#define M_MOD  64
#define T_CTX  16

// ---- workspace layout (bytes) ----
// Zbt : [64][N] bf16 (transposed Z)    @ 0            33,554,432
// SS  : [16][64][64] f32               @ ZB_BYTES        262,144
// Bm  : [16][64] f32                                       4,096
// wsum: [16] f32                                              64
// Pss : [256][16][64][64] bf16 (big path only)         33,554,432
#define ZB_OFF   ((size_t)0)
#define ZB_BYTES ((size_t)M_MOD * N_ROWS * 2)
#define SS_OFF   (ZB_OFF + ZB_BYTES)
#define SS_BYTES ((size_t)T_CTX * M_MOD * M_MOD * 4)
#define B_OFF    (SS_OFF + SS_BYTES)
#define B_BYTES  ((size_t)T_CTX * M_MOD * 4)
#define WS_OFF   (B_OFF + B_BYTES)
#define WS_BYTES ((size_t)64)
#define PSS_OFF  (WS_OFF + WS_BYTES)
#define PSS_BYTES ((size_t)256 * T_CTX * M_MOD * M_MOD * 2)
#define NEED_BIG (PSS_OFF + PSS_BYTES)

typedef __attribute__((ext_vector_type(8))) short short8;
typedef __attribute__((ext_vector_type(4))) float f32x4;

__device__ __forceinline__ float bf2f(unsigned short u) {
  return __uint_as_float(((unsigned int)u) << 16);
}
__device__ __forceinline__ unsigned short f2bf(float f) {
  unsigned int x = __float_as_uint(f);
  return (unsigned short)((x + 0x7fffu + ((x >> 16) & 1u)) >> 16);  // RNE
}
__device__ __forceinline__ unsigned int cvt_pk_bf16(float lo, float hi) {
  unsigned int r;
  asm("v_cvt_pk_bf16_f32 %0, %1, %2" : "=v"(r) : "v"(lo), "v"(hi));
  return r;
}
union U4S8 { uint4 u; short8 s; };

// ---------------- Z^T = (Y @ Mp^T)^T, stored bf16 as Zbt[m][n] ----------------
__global__ __launch_bounds__(512) void zk_kernel(
    const float* __restrict__ Y, const float* __restrict__ Mp,
    unsigned short* __restrict__ Zbt)
{
  __shared__ float Ylds[64][132];
  const int tid  = threadIdx.x;
  const int lane = tid & 63;
  const int wave = tid >> 6;
  const size_t ybase = (size_t)blockIdx.x * 64 * D_OUTC;
  const float4* Yg = (const float4*)(Y + ybase);
#pragma unroll
  for (int i = 0; i < 4; ++i) {
    int f4  = i * 512 + tid;
    int row = f4 >> 5;
    int kq  = f4 & 31;
    float4 v = Yg[f4];
    *(float4*)&Ylds[row][kq * 4] = v;
  }
  __syncthreads();
  const int m0 = __builtin_amdgcn_readfirstlane(wave * 8);
  float acc[8];
#pragma unroll
  for (int j = 0; j < 8; ++j) acc[j] = 0.f;
  for (int kc = 0; kc < 16; ++kc) {
    const int k0 = kc * 8;
    float4 y0 = *(const float4*)&Ylds[lane][k0];
    float4 y1 = *(const float4*)&Ylds[lane][k0 + 4];
    float y[8] = {y0.x, y0.y, y0.z, y0.w, y1.x, y1.y, y1.z, y1.w};
#pragma unroll
    for (int j = 0; j < 8; ++j) {
      const float* __restrict__ mr = Mp + (size_t)(m0 + j) * D_OUTC + k0;
#pragma unroll
      for (int kk = 0; kk < 8; ++kk)
        acc[j] = fmaf(y[kk], mr[kk], acc[j]);
    }
  }
  const size_t n = (size_t)blockIdx.x * 64 + lane;
#pragma unroll
  for (int j = 0; j < 8; ++j)
    Zbt[(size_t)(m0 + j) * N_ROWS + n] = f2bf(acc[j]);
}

// ---------------- SS (+B +wsum) via bf16 MFMA ----------------
// 256 blocks x 1024 thr; wave = context; 1024 rows/block in 64-row chunks.
// S_t += (w_t .* Z)^T @ Z : A-frag = bf16(w*z), B-frag = raw z (same LDS reads).
#define SS_BLOCKS 256
#define SS_ROWSB  (N_ROWS / SS_BLOCKS)   // 1024
template <bool PARTIAL>
__global__ __launch_bounds__(1024, 1) void ss_kernel(
    const unsigned short* __restrict__ Zbt, const float* __restrict__ W,
    float* __restrict__ SS, float* __restrict__ Bm, float* __restrict__ wsum,
    unsigned short* __restrict__ Pss)
{
  __shared__ unsigned short Zt[64][72];  // [m][n] bf16, stride 72 => 16B rows, 2-way banks
  __shared__ float Wl[16][68];           // [t][n] f32
  const int tid = threadIdx.x;
  const int l   = tid & 63;
  const int wv  = tid >> 6;        // wave id == context t
  const int g   = l >> 4;          // k-group (n-subrange)
  const int col = l & 15;

  f32x4 acc[4][4];
#pragma unroll
  for (int a = 0; a < 4; ++a)
#pragma unroll
    for (int b = 0; b < 4; ++b) acc[a][b] = (f32x4){0.f, 0.f, 0.f, 0.f};
  float bacc[4] = {0.f, 0.f, 0.f, 0.f};
  float wacc = 0.f;

  const int sm = tid >> 4, sq = tid & 15;   // staging roles

  for (int chunk = 0; chunk < SS_ROWSB / 64; ++chunk) {
    const int n0 = blockIdx.x * SS_ROWSB + chunk * 64;
    __syncthreads();
    // stage Z^T chunk: Zt[m][0..63] <- Zbt[m][n0..n0+63]  (global 128B/row, coalesced)
    *(uint2*)&Zt[sm][sq * 4] = *(const uint2*)(Zbt + (size_t)sm * N_ROWS + n0 + sq * 4);
    // stage W chunk transposed: Wl[t][n] <- W[n0+n][t]   (fully coalesced read)
    Wl[sq][sm] = W[(size_t)(n0 + sm) * T_CTX + sq];
    __syncthreads();
#pragma unroll
    for (int s = 0; s < 2; ++s) {
      const int nb = s * 32 + g * 8;
      float4 w0 = *(const float4*)&Wl[wv][nb];
      float4 w1 = *(const float4*)&Wl[wv][nb + 4];
      float w[8] = {w0.x, w0.y, w0.z, w0.w, w1.x, w1.y, w1.z, w1.w};
      wacc += ((w[0] + w[1]) + (w[2] + w[3])) + ((w[4] + w[5]) + (w[6] + w[7]));
      uint4 fr[4];
#pragma unroll
      for (int qi = 0; qi < 4; ++qi)
        fr[qi] = *(const uint4*)&Zt[qi * 16 + col][nb];
#pragma unroll
      for (int qi = 0; qi < 4; ++qi) {
        const unsigned int* u = (const unsigned int*)&fr[qi];
        float zf[8], af[8];
#pragma unroll
        for (int j = 0; j < 4; ++j) {
          zf[2 * j]     = __uint_as_float(u[j] << 16);
          zf[2 * j + 1] = __uint_as_float(u[j] & 0xffff0000u);
        }
#pragma unroll
        for (int e = 0; e < 8; ++e) af[e] = zf[e] * w[e];
        bacc[qi] += ((af[0] + af[1]) + (af[2] + af[3])) + ((af[4] + af[5]) + (af[6] + af[7]));
        U4S8 A;
#pragma unroll
        for (int j = 0; j < 4; ++j) A.u.x = 0;  // placate init; overwritten below
        A.u.x = cvt_pk_bf16(af[0], af[1]);
        A.u.y = cvt_pk_bf16(af[2], af[3]);
        A.u.z = cvt_pk_bf16(af[4], af[5]);
        A.u.w = cvt_pk_bf16(af[6], af[7]);
#pragma unroll
        for (int ki = 0; ki < 4; ++ki) {
          U4S8 B; B.u = fr[ki];
          acc[qi][ki] = __builtin_amdgcn_mfma_f32_16x16x32_bf16(A.s, B.s, acc[qi][ki], 0, 0, 0);
        }
      }
    }
  }

  // ---- B fold: bacc[qi] holds partial sum for m = qi*16 + col over this lane's n's
#pragma unroll
  for (int qi = 0; qi < 4; ++qi) {
    float v = bacc[qi];
    v += __shfl_xor(v, 16);
    v += __shfl_xor(v, 32);
    if (l < 16) atomicAdd(&Bm[wv * 64 + qi * 16 + l], v);
  }
  // ---- wsum fold
  {
    float v = wacc;
    v += __shfl_xor(v, 16);
    v += __shfl_xor(v, 32);
    if (l == 0) atomicAdd(&wsum[wv], v);
  }
  // ---- SS tiles out. C layout: col=lane&15, row=(lane>>4)*4+i
  if (PARTIAL) {
    unsigned short* P = Pss + ((size_t)blockIdx.x * 16 + wv) * 4096;
#pragma unroll
    for (int mi = 0; mi < 4; ++mi)
#pragma unroll
      for (int ki = 0; ki < 4; ++ki)
#pragma unroll
        for (int i = 0; i < 4; ++i) {
          int m = mi * 16 + g * 4 + i;
          int k = ki * 16 + col;
          P[m * 64 + k] = f2bf(acc[mi][ki][i]);
        }
  } else {
#pragma unroll
    for (int mi = 0; mi < 4; ++mi)
#pragma unroll
      for (int ki = 0; ki < 4; ++ki)
#pragma unroll
        for (int i = 0; i < 4; ++i) {
          int m = mi * 16 + g * 4 + i;
          int k = ki * 16 + col;
          atomicAdd(&SS[(size_t)wv * 4096 + m * 64 + k], acc[mi][ki][i]);
        }
  }
}

// ---------------- reduce bf16 partials -> SS f32 ----------------
__global__ __launch_bounds__(1024) void ssred_kernel(
    const unsigned short* __restrict__ Pss, float* __restrict__ SS)
{
  const int e = blockIdx.x * 1024 + threadIdx.x;   // 65536 total
  float s = 0.f;
#pragma unroll 8
  for (int b = 0; b < 256; ++b)
    s += bf2f(Pss[(size_t)b * 65536 + e]);
  SS[e] = s;
}

// ---------------- finalize ----------------
__global__ __launch_bounds__(1024) void fin_kernel(
    const float* __restrict__ SS, const float* __restrict__ Bm,
    const float* __restrict__ wsum, const float* __restrict__ Cp,
    const float* __restrict__ emaS, const unsigned char* __restrict__ inited,
    float* __restrict__ out)
{
  __shared__ float mu[16][64];
  __shared__ float stdl[16][64];
  __shared__ float red[16][64];
  __shared__ float wsl[16];
  const int tid = threadIdx.x;
  const int t = tid >> 6, m = tid & 63;
  if (tid < 16) wsl[tid] = wsum[tid];
  __syncthreads();
  const float ws = wsl[t];
  const float inv_ws = 1.0f / ws;
  const float mu_tm = Bm[t * 64 + m] * inv_ws;
  mu[t][m] = mu_tm;
  __syncthreads();
  {
    float Smm = SS[(size_t)t * 4096 + m * 64 + m] * inv_ws - mu_tm * mu_tm;
    float de  = 0.9f * emaS[(size_t)t * 4096 + m * 64 + m] + 0.1f * Smm;
    float sq  = inited[t] ? de : Smm;
    stdl[t][m] = sqrtf(sq + 1e-6f);
  }
  __syncthreads();
  const float sm = stdl[t][m];
  float acc = 0.f;
  for (int k = 0; k < 64; ++k) {
    float Sig = SS[(size_t)t * 4096 + m * 64 + k] * inv_ws - mu_tm * mu[t][k];
    float den = sm * stdl[t][k] + 1e-6f;
    float ch  = Sig / den;
    ch = fminf(1.f, fmaxf(-1.f, ch));
    float d = ch - Cp[(size_t)t * 4096 + m * 64 + k];
    acc = fmaf(d, d, acc);
  }
  red[t][m] = acc;
  __syncthreads();
  if (tid < 16) {
    float s = 0.f;
    for (int mm = 0; mm < 64; ++mm) s += red[tid][mm];
    red[tid][0] = s / wsl[tid];
  }
  __syncthreads();
  if (tid == 0) {
    int na = 0; float tot = 0.f;
    for (int tt = 0; tt < 16; ++tt) {
      if (wsl[tt] >= 30.0f) { na++; tot += red[tt][0]; }
    }
    out[0] = (na > 0) ? (0.1f * 1.0f * tot / (float)na) : 0.f;
  }
}

extern "C" void kernel_launch(void* const* d_in, const int* in_sizes, int n_in,
                              void* d_out, int out_size, void* d_ws, size_t ws_size,
                              hipStream_t stream) {
  (void)in_sizes; (void)n_in; (void)out_size;
  const float* Y    = (const float*)d_in[0];
  const float* W    = (const float*)d_in[1];
  const float* Mp   = (const float*)d_in[2];
  const float* Cp   = (const float*)d_in[3];
  const float* emaS = (const float*)d_in[4];
  const unsigned char* inited = (const unsigned char*)d_in[6];
  float* out = (float*)d_out;
  char* ws = (char*)d_ws;
  unsigned short* Zbt = (unsigned short*)(ws + ZB_OFF);
  float* SS   = (float*)(ws + SS_OFF);
  float* Bm   = (float*)(ws + B_OFF);
  float* wsum = (float*)(ws + WS_OFF);
  unsigned short* Pss = (unsigned short*)(ws + PSS_OFF);

  zk_kernel<<<N_ROWS / 64, 512, 0, stream>>>(Y, Mp, Zbt);
  if (ws_size >= NEED_BIG) {
    hipMemsetAsync(ws + B_OFF, 0, B_BYTES + WS_BYTES, stream);
    ss_kernel<true><<<SS_BLOCKS, 1024, 0, stream>>>(Zbt, W, SS, Bm, wsum, Pss);
    ssred_kernel<<<64, 1024, 0, stream>>>(Pss, SS);
  } else {
    hipMemsetAsync(ws + SS_OFF, 0, SS_BYTES + B_BYTES + WS_BYTES, stream);
    ss_kernel<false><<<SS_BLOCKS, 1024, 0, stream>>>(Zbt, W, SS, Bm, wsum, Pss);
  }
  fin_kernel<<<1, 1024, 0, stream>>>(SS, Bm, wsum, Cp, emaS, inited, out);
}

// Round 4
// 177.315 us; speedup vs baseline: 5.8396x; 1.3237x over previous
//
#include <hip/hip_runtime.h>
#include <stdint.h>

#define N_ROWS 262144
#define D_OUTC 128
#define M_MOD  64
#define T_CTX  16

// ---- workspace layout (bytes) ----
#define ZB_OFF   ((size_t)0)
#define ZB_BYTES ((size_t)M_MOD * N_ROWS * 2)          // Zt[m][n] f16  33.5MB
#define SS_OFF   (ZB_OFF + ZB_BYTES)
#define SS_BYTES ((size_t)T_CTX * M_MOD * M_MOD * 4)   // 262144
#define B_OFF    (SS_OFF + SS_BYTES)
#define B_BYTES  ((size_t)T_CTX * M_MOD * 4)           // 4096
#define WSUM_OFF (B_OFF + B_BYTES)
#define WSUM_BYTES ((size_t)64)
#define LT_OFF   (WSUM_OFF + WSUM_BYTES)
#define LT_BYTES ((size_t)64)
#define PSS_OFF  (LT_OFF + LT_BYTES)
#define PSS_BYTES ((size_t)256 * T_CTX * M_MOD * M_MOD * 2)  // 33.5MB bf16 partials
#define NEED_BIG (PSS_OFF + PSS_BYTES)

typedef __attribute__((ext_vector_type(4))) float f32x4;
typedef __attribute__((ext_vector_type(2))) float f32x2;
typedef __attribute__((ext_vector_type(8))) _Float16 f16x8;
typedef __attribute__((ext_vector_type(2))) _Float16 h2;

union FR { uint4 u; f16x8 v; h2 h[4]; };

__device__ __forceinline__ float bf2f(unsigned short u) {
  return __uint_as_float(((unsigned int)u) << 16);
}
__device__ __forceinline__ unsigned short f2bf(float f) {
  unsigned int x = __float_as_uint(f);
  return (unsigned short)((x + 0x7fffu + ((x >> 16) & 1u)) >> 16);  // RNE
}
__device__ __forceinline__ h2 cvt_pkrtz(float a, float b) {
  return __builtin_bit_cast(h2, __builtin_amdgcn_cvt_pkrtz(a, b));
}

#if __has_builtin(__builtin_amdgcn_fdot2)
__device__ __forceinline__ float fdot2f(h2 a, h2 b, float c) {
  return __builtin_amdgcn_fdot2(a, b, c, false);
}
#else
__device__ __forceinline__ float fdot2f(h2 a, h2 b, float c) {
  return c + (float)a[0] * (float)b[0] + (float)a[1] * (float)b[1];
}
#endif

// ---------------- Z^T = (Y @ Mp^T)^T, f16, Zbt[m][n] ----------------
// 512 thr, 64 n-rows/block. Packed f32 FMA (v_pk_fma_f32); swizzled Y LDS.
__global__ __launch_bounds__(512) void zk_kernel(
    const float* __restrict__ Y, const float* __restrict__ Mp,
    _Float16* __restrict__ Zbt)
{
  __shared__ __align__(16) float Yl[64 * 128];  // swizzled: fidx = row*128 + (k ^ ((row&7)<<2))
  const int tid  = threadIdx.x;
  const int lane = tid & 63;
  const int wave = tid >> 6;
  const size_t ybase = (size_t)blockIdx.x * 64 * D_OUTC;
  const float4* Yg = (const float4*)(Y + ybase);
#pragma unroll
  for (int i = 0; i < 4; ++i) {
    int f4  = i * 512 + tid;      // 0..2047
    int row = f4 >> 5;
    int kq  = f4 & 31;            // float4 slot
    float4 v = Yg[f4];
    int idx = row * 128 + ((4 * kq) ^ ((row & 7) << 2));
    *(float4*)&Yl[idx] = v;
  }
  __syncthreads();
  const int m0 = __builtin_amdgcn_readfirstlane(wave * 8);
  const int sw = (lane & 7) << 2;
  f32x2 acc2[8];
#pragma unroll
  for (int j = 0; j < 8; ++j) acc2[j] = (f32x2){0.f, 0.f};
  for (int kc = 0; kc < 16; ++kc) {
    const int k0 = kc * 8;
    float4 y0 = *(const float4*)&Yl[lane * 128 + (k0 ^ sw)];
    float4 y1 = *(const float4*)&Yl[lane * 128 + ((k0 + 4) ^ sw)];
    f32x2 yp[4] = {{y0.x, y0.y}, {y0.z, y0.w}, {y1.x, y1.y}, {y1.z, y1.w}};
#pragma unroll
    for (int j = 0; j < 8; ++j) {
      const float* __restrict__ mr = Mp + (size_t)(m0 + j) * D_OUTC + k0;
#pragma unroll
      for (int p = 0; p < 4; ++p)
        acc2[j] += yp[p] * (f32x2){mr[2 * p], mr[2 * p + 1]};
    }
  }
  const size_t n = (size_t)blockIdx.x * 64 + lane;
#pragma unroll
  for (int j = 0; j < 8; ++j)
    Zbt[(size_t)(m0 + j) * N_ROWS + n] = (_Float16)(acc2[j].x + acc2[j].y);
}

// ---------------- SS (+B +wsum) via f16 MFMA, pipelined gload_lds ----------------
// 256 blocks x 1024 thr (wave = context); 1024 rows/block in 128-n chunks, dbuf.
#define SS_BLOCKS 256
template <bool PARTIAL>
__global__ __launch_bounds__(1024, 1) void ss_kernel(
    const _Float16* __restrict__ Zbt, const float* __restrict__ W,
    float* __restrict__ SS, float* __restrict__ Bm, float* __restrict__ wsum,
    unsigned short* __restrict__ Pss)
{
  // Zl: [64 m][128 n] f16, rows 256B, byte-swizzle c' = c ^ ((m&7)<<4)
  __shared__ __align__(16) _Float16 Zl[2][64 * 128];
  __shared__ float Wl[2][16][132];   // [t][n] f32
  const int tid = threadIdx.x;
  const int l   = tid & 63;
  const int wv  = tid >> 6;          // wave id == context t
  const int g   = l >> 4;
  const int col = l & 15;
  const int swz = (col & 7) << 4;    // byte units
  const int n0b = blockIdx.x * 1024;

  // Z staging: wave wv stages rows 4wv..4wv+3; lane i -> dest byte wv*1024 + i*16
  const int zm    = 4 * wv + (l >> 4);
  const int zslot = l & 15;
  const _Float16* zsrc = Zbt + (size_t)zm * N_ROWS + n0b + 8 * (zslot ^ (zm & 7));
  // W staging: 2 f32/thread
  const int r0w = tid >> 4, t0w = tid & 15;   // idx = tid        -> row r0w
  const int r1w = r0w + 64;                    // idx = tid + 1024 -> row r0w+64, same t

  f32x4 acc[4][4];
#pragma unroll
  for (int a = 0; a < 4; ++a)
#pragma unroll
    for (int b = 0; b < 4; ++b) acc[a][b] = (f32x4){0.f, 0.f, 0.f, 0.f};
  float bacc[4] = {0.f, 0.f, 0.f, 0.f};
  float wacc = 0.f;
  const h2 one2 = {(_Float16)1.f, (_Float16)1.f};

  // prologue: stage chunk 0
  __builtin_amdgcn_global_load_lds((const unsigned int*)zsrc,
                                   (unsigned int*)&Zl[0][wv * 512], 16, 0, 0);
  {
    float w0 = W[(size_t)(n0b + r0w) * T_CTX + t0w];
    float w1 = W[(size_t)(n0b + r1w) * T_CTX + t0w];
    Wl[0][t0w][r0w] = w0;
    Wl[0][t0w][r1w] = w1;
  }
  __syncthreads();

  for (int c = 0; c < 8; ++c) {
    const int buf = c & 1;
    float wr0 = 0.f, wr1 = 0.f;
    if (c < 7) {
      const int n1 = n0b + (c + 1) * 128;
      __builtin_amdgcn_global_load_lds((const unsigned int*)(zsrc + (c + 1) * 128),
                                       (unsigned int*)&Zl[buf ^ 1][wv * 512], 16, 0, 0);
      wr0 = W[(size_t)(n1 + r0w) * T_CTX + t0w];
      wr1 = W[(size_t)(n1 + r1w) * T_CTX + t0w];
    }
    const char* zbase = (const char*)&Zl[buf][0];
#pragma unroll
    for (int s = 0; s < 4; ++s) {
      const float* wrow = &Wl[buf][wv][s * 32 + g * 8];
      float4 w0 = *(const float4*)wrow;
      float4 w1 = *(const float4*)(wrow + 4);
      h2 wpk[4];
      wpk[0] = cvt_pkrtz(w0.x, w0.y);
      wpk[1] = cvt_pkrtz(w0.z, w0.w);
      wpk[2] = cvt_pkrtz(w1.x, w1.y);
      wpk[3] = cvt_pkrtz(w1.z, w1.w);
#pragma unroll
      for (int j = 0; j < 4; ++j) wacc = fdot2f(wpk[j], one2, wacc);
      const int cby = ((s * 64 + g * 16) ^ swz);
      FR fr[4];
#pragma unroll
      for (int qi = 0; qi < 4; ++qi)
        fr[qi].u = *(const uint4*)(zbase + (qi * 16 + col) * 256 + cby);
#pragma unroll
      for (int qi = 0; qi < 4; ++qi) {
        FR A;
#pragma unroll
        for (int j = 0; j < 4; ++j) {
          A.h[j] = fr[qi].h[j] * wpk[j];
          bacc[qi] = fdot2f(fr[qi].h[j], wpk[j], bacc[qi]);
        }
#pragma unroll
        for (int ki = 0; ki < 4; ++ki)
          acc[qi][ki] = __builtin_amdgcn_mfma_f32_16x16x32_f16(A.v, fr[ki].v, acc[qi][ki], 0, 0, 0);
      }
    }
    if (c < 7) {
      Wl[buf ^ 1][t0w][r0w] = wr0;
      Wl[buf ^ 1][t0w][r1w] = wr1;
    }
    __syncthreads();   // drains own vmcnt (gload_lds + wr) and lgkm; syncs buffers
  }

  // ---- B fold
#pragma unroll
  for (int qi = 0; qi < 4; ++qi) {
    float v = bacc[qi];
    v += __shfl_xor(v, 16);
    v += __shfl_xor(v, 32);
    if (l < 16) atomicAdd(&Bm[wv * 64 + qi * 16 + l], v);
  }
  {
    float v = wacc;
    v += __shfl_xor(v, 16);
    v += __shfl_xor(v, 32);
    if (l == 0) atomicAdd(&wsum[wv], v);
  }
  // ---- SS tiles out. C layout: col=lane&15 (k), row=(lane>>4)*4+i (m within tile)
  if (PARTIAL) {
    unsigned short* P = Pss + ((size_t)blockIdx.x * 16 + wv) * 4096;
#pragma unroll
    for (int qi = 0; qi < 4; ++qi)
#pragma unroll
      for (int ki = 0; ki < 4; ++ki)
#pragma unroll
        for (int i = 0; i < 4; ++i)
          P[(qi * 16 + g * 4 + i) * 64 + ki * 16 + col] = f2bf(acc[qi][ki][i]);
  } else {
#pragma unroll
    for (int qi = 0; qi < 4; ++qi)
#pragma unroll
      for (int ki = 0; ki < 4; ++ki)
#pragma unroll
        for (int i = 0; i < 4; ++i)
          atomicAdd(&SS[(size_t)wv * 4096 + (qi * 16 + g * 4 + i) * 64 + ki * 16 + col],
                    acc[qi][ki][i]);
  }
}

// ---------------- reduce bf16 partials -> SS f32 ----------------
__global__ __launch_bounds__(256) void ssred_kernel(
    const unsigned short* __restrict__ Pss, float* __restrict__ SS)
{
  const int e = blockIdx.x * 256 + threadIdx.x;   // 65536 total
  float s = 0.f;
#pragma unroll 8
  for (int b = 0; b < 256; ++b)
    s += bf2f(Pss[(size_t)b * 65536 + e]);
  SS[e] = s;
}

// ---------------- finalize part 1: per-context loss_t ----------------
__global__ __launch_bounds__(64) void fin1_kernel(
    const float* __restrict__ SS, const float* __restrict__ Bm,
    const float* __restrict__ wsum, const float* __restrict__ Cp,
    const float* __restrict__ emaS, const unsigned char* __restrict__ inited,
    float* __restrict__ LT)
{
  const int t = blockIdx.x, m = threadIdx.x;
  __shared__ float muL[64], stdL[64];
  const float ws  = wsum[t];
  const float inv = 1.0f / ws;
  const float mu  = Bm[t * 64 + m] * inv;
  {
    float Smm = SS[(size_t)t * 4096 + m * 65] * inv - mu * mu;
    float de  = 0.9f * emaS[(size_t)t * 4096 + m * 65] + 0.1f * Smm;
    float sq  = inited[t] ? de : Smm;
    muL[m]  = mu;
    stdL[m] = sqrtf(sq + 1e-6f);
  }
  __syncthreads();
  const float sm = stdL[m];
  const float* SSr = SS + (size_t)t * 4096 + m * 64;
  const float* Cpr = Cp + (size_t)t * 4096 + m * 64;
  float acc = 0.f;
#pragma unroll
  for (int k = 0; k < 64; ++k) {
    float Sig = SSr[k] * inv - mu * muL[k];
    float den = sm * stdL[k] + 1e-6f;
    float ch  = fminf(1.f, fmaxf(-1.f, Sig / den));
    float d   = ch - Cpr[k];
    acc = fmaf(d, d, acc);
  }
#pragma unroll
  for (int o = 1; o < 64; o <<= 1) acc += __shfl_xor(acc, o);
  if (m == 0) LT[t] = acc * inv;
}

// ---------------- finalize part 2: scalar ----------------
__global__ __launch_bounds__(64) void fin2_kernel(
    const float* __restrict__ LT, const float* __restrict__ wsum,
    float* __restrict__ out)
{
  const int l = threadIdx.x;
  float lt = 0.f;
  float act = 0.f;
  if (l < 16) {
    float ws = wsum[l];
    if (ws >= 30.0f) { act = 1.f; lt = LT[l]; }
  }
#pragma unroll
  for (int o = 1; o < 16; o <<= 1) {
    lt  += __shfl_xor(lt, o);
    act += __shfl_xor(act, o);
  }
  if (l == 0) out[0] = (act > 0.f) ? (0.1f * 1.0f * lt / act) : 0.f;
}

extern "C" void kernel_launch(void* const* d_in, const int* in_sizes, int n_in,
                              void* d_out, int out_size, void* d_ws, size_t ws_size,
                              hipStream_t stream) {
  (void)in_sizes; (void)n_in; (void)out_size;
  const float* Y    = (const float*)d_in[0];
  const float* W    = (const float*)d_in[1];
  const float* Mp   = (const float*)d_in[2];
  const float* Cp   = (const float*)d_in[3];
  const float* emaS = (const float*)d_in[4];
  const unsigned char* inited = (const unsigned char*)d_in[6];
  float* out = (float*)d_out;
  char* ws = (char*)d_ws;
  _Float16* Zbt = (_Float16*)(ws + ZB_OFF);
  float* SS   = (float*)(ws + SS_OFF);
  float* Bm   = (float*)(ws + B_OFF);
  float* wsum = (float*)(ws + WSUM_OFF);
  float* LT   = (float*)(ws + LT_OFF);
  unsigned short* Pss = (unsigned short*)(ws + PSS_OFF);

  (void)hipMemsetAsync(ws + SS_OFF, 0, SS_BYTES + B_BYTES + WSUM_BYTES, stream);
  zk_kernel<<<N_ROWS / 64, 512, 0, stream>>>(Y, Mp, Zbt);
  if (ws_size >= NEED_BIG) {
    ss_kernel<true><<<SS_BLOCKS, 1024, 0, stream>>>(Zbt, W, SS, Bm, wsum, Pss);
    ssred_kernel<<<256, 256, 0, stream>>>(Pss, SS);
  } else {
    ss_kernel<false><<<SS_BLOCKS, 1024, 0, stream>>>(Zbt, W, SS, Bm, wsum, Pss);
  }
  fin1_kernel<<<16, 64, 0, stream>>>(SS, Bm, wsum, Cp, emaS, inited, LT);
  fin2_kernel<<<1, 64, 0, stream>>>(LT, wsum, out);
}

// Round 5
// 166.674 us; speedup vs baseline: 6.2124x; 1.0638x over previous
//
#include <hip/hip_runtime.h>
#include <stdint.h>

#define N_ROWS 262144
#define D_OUTC 128
#define M_MOD  64
#define T_CTX  16

// ---- workspace layout (bytes) ----
#define ZB_OFF   ((size_t)0)
#define ZB_BYTES ((size_t)M_MOD * N_ROWS * 2)          // Zt[m][n] f16  33.5MB
#define WT_OFF   (ZB_OFF + ZB_BYTES)
#define WT_BYTES ((size_t)T_CTX * N_ROWS * 2)          // Wt[t][n] f16  8.4MB
#define SS_OFF   (WT_OFF + WT_BYTES)
#define SS_BYTES ((size_t)T_CTX * M_MOD * M_MOD * 4)   // 262144
#define B_OFF    (SS_OFF + SS_BYTES)
#define B_BYTES  ((size_t)T_CTX * M_MOD * 4)           // 4096
#define WSUM_OFF (B_OFF + B_BYTES)
#define WSUM_BYTES ((size_t)64)
#define LT_OFF   (WSUM_OFF + WSUM_BYTES)
#define LT_BYTES ((size_t)64)
#define PSS_OFF  (LT_OFF + LT_BYTES)
#define PSS_BYTES ((size_t)256 * T_CTX * M_MOD * M_MOD * 2)  // 33.5MB bf16 partials
#define NEED_BIG (PSS_OFF + PSS_BYTES)

typedef __attribute__((ext_vector_type(4))) float f32x4;
typedef __attribute__((ext_vector_type(2))) float f32x2;
typedef __attribute__((ext_vector_type(8))) _Float16 f16x8;
typedef __attribute__((ext_vector_type(2))) _Float16 h2;

union FR { uint4 u; f16x8 v; h2 h[4]; };

__device__ __forceinline__ float bf2f(unsigned short u) {
  return __uint_as_float(((unsigned int)u) << 16);
}
__device__ __forceinline__ unsigned short f2bf(float f) {
  unsigned int x = __float_as_uint(f);
  return (unsigned short)((x + 0x7fffu + ((x >> 16) & 1u)) >> 16);  // RNE
}
__device__ __forceinline__ h2 cvt_pkrtz(float a, float b) {
  return __builtin_bit_cast(h2, __builtin_amdgcn_cvt_pkrtz(a, b));
}

#if __has_builtin(__builtin_amdgcn_fdot2)
__device__ __forceinline__ float fdot2f(h2 a, h2 b, float c) {
  return __builtin_amdgcn_fdot2(a, b, c, false);
}
#else
__device__ __forceinline__ float fdot2f(h2 a, h2 b, float c) {
  return c + (float)a[0] * (float)b[0] + (float)a[1] * (float)b[1];
}
#endif

// ---------------- Z^T = (Y @ Mp^T)^T f16 Zbt[m][n]; also Wt[t][n] f16 ----------------
__global__ __launch_bounds__(512) void zk_kernel(
    const float* __restrict__ Y, const float* __restrict__ Mp,
    const float* __restrict__ W,
    _Float16* __restrict__ Zbt, _Float16* __restrict__ Wt)
{
  __shared__ __align__(16) float Yl[64 * 128];  // swizzled: fidx = row*128 + (k ^ ((row&7)<<2))
  __shared__ float Wf[16][66];
  const int tid  = threadIdx.x;
  const int lane = tid & 63;
  const int wave = tid >> 6;
  const int n0   = blockIdx.x * 64;
  const size_t ybase = (size_t)n0 * D_OUTC;
  const float4* Yg = (const float4*)(Y + ybase);
#pragma unroll
  for (int i = 0; i < 4; ++i) {
    int f4  = i * 512 + tid;      // 0..2047
    int row = f4 >> 5;
    int kq  = f4 & 31;            // float4 slot
    float4 v = Yg[f4];
    int idx = row * 128 + ((4 * kq) ^ ((row & 7) << 2));
    *(float4*)&Yl[idx] = v;
  }
  // W slice [64 rows][16] -> Wf transposed
  {
    float2 w2 = *(const float2*)(W + (size_t)n0 * T_CTX + 2 * tid);
    Wf[(tid & 7) * 2 + 0][tid >> 3] = w2.x;
    Wf[(tid & 7) * 2 + 1][tid >> 3] = w2.y;
  }
  __syncthreads();
  // Wt out: thread covers (t = tid>>5, ni = tid&31) -> 2 n's
  {
    int t = tid >> 5, ni = tid & 31;
    h2 wh = cvt_pkrtz(Wf[t][2 * ni], Wf[t][2 * ni + 1]);
    *(h2*)(Wt + (size_t)t * N_ROWS + n0 + 2 * ni) = wh;
  }
  const int m0 = __builtin_amdgcn_readfirstlane(wave * 8);
  const int sw = (lane & 7) << 2;
  f32x2 acc2[8];
#pragma unroll
  for (int j = 0; j < 8; ++j) acc2[j] = (f32x2){0.f, 0.f};
  for (int kc = 0; kc < 16; ++kc) {
    const int k0 = kc * 8;
    float4 y0 = *(const float4*)&Yl[lane * 128 + (k0 ^ sw)];
    float4 y1 = *(const float4*)&Yl[lane * 128 + ((k0 + 4) ^ sw)];
    f32x2 yp[4] = {{y0.x, y0.y}, {y0.z, y0.w}, {y1.x, y1.y}, {y1.z, y1.w}};
#pragma unroll
    for (int j = 0; j < 8; ++j) {
      const float* __restrict__ mr = Mp + (size_t)(m0 + j) * D_OUTC + k0;
#pragma unroll
      for (int p = 0; p < 4; ++p)
        acc2[j] += yp[p] * (f32x2){mr[2 * p], mr[2 * p + 1]};
    }
  }
  const size_t n = (size_t)n0 + lane;
#pragma unroll
  for (int j = 0; j < 8; ++j)
    Zbt[(size_t)(m0 + j) * N_ROWS + n] = (_Float16)(acc2[j].x + acc2[j].y);
}

// ---------------- SS (+B +wsum) via f16 MFMA ----------------
// grid 1024 = 256 n-splits x 4 ctx-groups; block 256 thr (4 waves, wave = 1 ctx).
// 1024 n-rows per block, 8 chunks of 128, dbuf gload_lds. 4 blocks/CU.
#define SS_NS 256
template <bool PARTIAL>
__global__ __launch_bounds__(256, 4) void ss_kernel(
    const _Float16* __restrict__ Zbt, const _Float16* __restrict__ Wt,
    float* __restrict__ SS, float* __restrict__ Bm, float* __restrict__ wsum,
    unsigned short* __restrict__ Pss)
{
  // Zl: [64 m][128 n] f16, rows 256B, byte-swizzle via pre-swizzled source
  __shared__ __align__(16) _Float16 Zl[2][64 * 128];
  __shared__ __align__(16) _Float16 Wl[2][4 * 128];   // [ctx-in-group][n]
  const int tid = threadIdx.x;
  const int l   = tid & 63;
  const int wv  = tid >> 6;          // wave id (0..3)
  const int g   = l >> 4;
  const int col = l & 15;
  const int swz = (col & 7) << 4;    // byte units
  const int ns  = blockIdx.x & (SS_NS - 1);
  const int cg  = blockIdx.x >> 8;   // 0..3
  const int ctx = cg * 4 + wv;
  const int n0b = ns * 1024;
  const int zslot = l & 15;
  const int zr    = l >> 4;          // 0..3

  f32x4 acc[4][4];
#pragma unroll
  for (int a = 0; a < 4; ++a)
#pragma unroll
    for (int b = 0; b < 4; ++b) acc[a][b] = (f32x4){0.f, 0.f, 0.f, 0.f};
  float bacc[4] = {0.f, 0.f, 0.f, 0.f};
  float wacc = 0.f;
  const h2 one2 = {(_Float16)1.f, (_Float16)1.f};

  auto stage = [&](int c, int buf) {
    const int n0 = n0b + c * 128;
#pragma unroll
    for (int i = 0; i < 4; ++i) {
      int zm = 16 * wv + 4 * i + zr;
      const _Float16* src = Zbt + (size_t)zm * N_ROWS + n0 + 8 * (zslot ^ (zm & 7));
      __builtin_amdgcn_global_load_lds((const unsigned int*)src,
          (unsigned int*)((char*)&Zl[buf][0] + (16 * wv + 4 * i) * 256), 16, 0, 0);
    }
    if (wv == 0) {
      const _Float16* wsrc = Wt + (size_t)(cg * 4 + zr) * N_ROWS + n0 + 8 * zslot;
      __builtin_amdgcn_global_load_lds((const unsigned int*)wsrc,
          (unsigned int*)((char*)&Wl[buf][0]), 16, 0, 0);
    }
  };

  stage(0, 0);
  __syncthreads();

  for (int c = 0; c < 8; ++c) {
    const int buf = c & 1;
    if (c < 7) stage(c + 1, buf ^ 1);
    const char* zb = (const char*)&Zl[buf][0];
    const char* wb = (const char*)&Wl[buf][0];
#pragma unroll
    for (int s = 0; s < 4; ++s) {
      FR wfr;
      wfr.u = *(const uint4*)(wb + wv * 256 + s * 64 + g * 16);
#pragma unroll
      for (int j = 0; j < 4; ++j) wacc = fdot2f(wfr.h[j], one2, wacc);
      const int cby = ((s * 64 + g * 16) ^ swz);
      FR fr[4];
#pragma unroll
      for (int qi = 0; qi < 4; ++qi)
        fr[qi].u = *(const uint4*)(zb + (qi * 16 + col) * 256 + cby);
#pragma unroll
      for (int qi = 0; qi < 4; ++qi) {
        FR A;
#pragma unroll
        for (int j = 0; j < 4; ++j) {
          A.h[j] = fr[qi].h[j] * wfr.h[j];
          bacc[qi] = fdot2f(fr[qi].h[j], wfr.h[j], bacc[qi]);
        }
#pragma unroll
        for (int ki = 0; ki < 4; ++ki)
          acc[qi][ki] = __builtin_amdgcn_mfma_f32_16x16x32_f16(A.v, fr[ki].v, acc[qi][ki], 0, 0, 0);
      }
    }
    __syncthreads();   // drains own vmcnt (gload_lds) ; swaps buffers
  }

  // ---- B fold: bacc[qi] partial for m = qi*16 + col
#pragma unroll
  for (int qi = 0; qi < 4; ++qi) {
    float v = bacc[qi];
    v += __shfl_xor(v, 16);
    v += __shfl_xor(v, 32);
    if (l < 16) atomicAdd(&Bm[ctx * 64 + qi * 16 + l], v);
  }
  {
    float v = wacc;
    v += __shfl_xor(v, 16);
    v += __shfl_xor(v, 32);
    if (l == 0) atomicAdd(&wsum[ctx], v);
  }
  // ---- SS tiles out. C layout: col=lane&15 (k), row=(lane>>4)*4+i
  if (PARTIAL) {
    unsigned short* P = Pss + ((size_t)ns * 16 + ctx) * 4096;
#pragma unroll
    for (int qi = 0; qi < 4; ++qi)
#pragma unroll
      for (int ki = 0; ki < 4; ++ki)
#pragma unroll
        for (int i = 0; i < 4; ++i)
          P[(qi * 16 + g * 4 + i) * 64 + ki * 16 + col] = f2bf(acc[qi][ki][i]);
  } else {
#pragma unroll
    for (int qi = 0; qi < 4; ++qi)
#pragma unroll
      for (int ki = 0; ki < 4; ++ki)
#pragma unroll
        for (int i = 0; i < 4; ++i)
          atomicAdd(&SS[(size_t)ctx * 4096 + (qi * 16 + g * 4 + i) * 64 + ki * 16 + col],
                    acc[qi][ki][i]);
  }
}

// ---------------- reduce bf16 partials -> SS f32 ----------------
__global__ __launch_bounds__(256) void ssred_kernel(
    const unsigned short* __restrict__ Pss, float* __restrict__ SS)
{
  const int e = blockIdx.x * 256 + threadIdx.x;   // 65536 total
  float s = 0.f;
#pragma unroll 8
  for (int b = 0; b < 256; ++b)
    s += bf2f(Pss[(size_t)b * 65536 + e]);
  SS[e] = s;
}

// ---------------- finalize part 1: per-context loss_t ----------------
__global__ __launch_bounds__(64) void fin1_kernel(
    const float* __restrict__ SS, const float* __restrict__ Bm,
    const float* __restrict__ wsum, const float* __restrict__ Cp,
    const float* __restrict__ emaS, const unsigned char* __restrict__ inited,
    float* __restrict__ LT)
{
  const int t = blockIdx.x, m = threadIdx.x;
  __shared__ float muL[64], stdL[64];
  const float ws  = wsum[t];
  const float inv = 1.0f / ws;
  const float mu  = Bm[t * 64 + m] * inv;
  {
    float Smm = SS[(size_t)t * 4096 + m * 65] * inv - mu * mu;
    float de  = 0.9f * emaS[(size_t)t * 4096 + m * 65] + 0.1f * Smm;
    float sq  = inited[t] ? de : Smm;
    muL[m]  = mu;
    stdL[m] = sqrtf(sq + 1e-6f);
  }
  __syncthreads();
  const float sm = stdL[m];
  const float* SSr = SS + (size_t)t * 4096 + m * 64;
  const float* Cpr = Cp + (size_t)t * 4096 + m * 64;
  float acc = 0.f;
#pragma unroll
  for (int k = 0; k < 64; ++k) {
    float Sig = SSr[k] * inv - mu * muL[k];
    float den = sm * stdL[k] + 1e-6f;
    float ch  = fminf(1.f, fmaxf(-1.f, Sig / den));
    float d   = ch - Cpr[k];
    acc = fmaf(d, d, acc);
  }
#pragma unroll
  for (int o = 1; o < 64; o <<= 1) acc += __shfl_xor(acc, o);
  if (m == 0) LT[t] = acc * inv;
}

// ---------------- finalize part 2: scalar ----------------
__global__ __launch_bounds__(64) void fin2_kernel(
    const float* __restrict__ LT, const float* __restrict__ wsum,
    float* __restrict__ out)
{
  const int l = threadIdx.x;
  float lt = 0.f;
  float act = 0.f;
  if (l < 16) {
    float ws = wsum[l];
    if (ws >= 30.0f) { act = 1.f; lt = LT[l]; }
  }
#pragma unroll
  for (int o = 1; o < 16; o <<= 1) {
    lt  += __shfl_xor(lt, o);
    act += __shfl_xor(act, o);
  }
  if (l == 0) out[0] = (act > 0.f) ? (0.1f * 1.0f * lt / act) : 0.f;
}

extern "C" void kernel_launch(void* const* d_in, const int* in_sizes, int n_in,
                              void* d_out, int out_size, void* d_ws, size_t ws_size,
                              hipStream_t stream) {
  (void)in_sizes; (void)n_in; (void)out_size;
  const float* Y    = (const float*)d_in[0];
  const float* W    = (const float*)d_in[1];
  const float* Mp   = (const float*)d_in[2];
  const float* Cp   = (const float*)d_in[3];
  const float* emaS = (const float*)d_in[4];
  const unsigned char* inited = (const unsigned char*)d_in[6];
  float* out = (float*)d_out;
  char* ws = (char*)d_ws;
  _Float16* Zbt = (_Float16*)(ws + ZB_OFF);
  _Float16* Wt  = (_Float16*)(ws + WT_OFF);
  float* SS   = (float*)(ws + SS_OFF);
  float* Bm   = (float*)(ws + B_OFF);
  float* wsum = (float*)(ws + WSUM_OFF);
  float* LT   = (float*)(ws + LT_OFF);
  unsigned short* Pss = (unsigned short*)(ws + PSS_OFF);

  (void)hipMemsetAsync(ws + SS_OFF, 0, SS_BYTES + B_BYTES + WSUM_BYTES, stream);
  zk_kernel<<<N_ROWS / 64, 512, 0, stream>>>(Y, Mp, W, Zbt, Wt);
  if (ws_size >= NEED_BIG) {
    ss_kernel<true><<<4 * SS_NS, 256, 0, stream>>>(Zbt, Wt, SS, Bm, wsum, Pss);
    ssred_kernel<<<256, 256, 0, stream>>>(Pss, SS);
  } else {
    ss_kernel<false><<<4 * SS_NS, 256, 0, stream>>>(Zbt, Wt, SS, Bm, wsum, Pss);
  }
  fin1_kernel<<<16, 64, 0, stream>>>(SS, Bm, wsum, Cp, emaS, inited, LT);
  fin2_kernel<<<1, 64, 0, stream>>>(LT, wsum, out);
}

// Round 6
// 150.073 us; speedup vs baseline: 6.8997x; 1.1106x over previous
//
#include <hip/hip_runtime.h>
#include <stdint.h>

#define N_ROWS 262144
#define D_OUTC 128
#define M_MOD  64
#define T_CTX  16

// ---- workspace layout (bytes) ----
#define ZB_OFF   ((size_t)0)
#define ZB_BYTES ((size_t)M_MOD * N_ROWS * 2)          // Zbt[m][n] f16  33.5MB
#define WT_OFF   (ZB_OFF + ZB_BYTES)
#define WT_BYTES ((size_t)T_CTX * N_ROWS * 2)          // Wt[t][n] f16  8.4MB
#define SS_OFF   (WT_OFF + WT_BYTES)
#define SS_BYTES ((size_t)T_CTX * M_MOD * M_MOD * 4)
#define B_OFF    (SS_OFF + SS_BYTES)
#define B_BYTES  ((size_t)T_CTX * M_MOD * 4)
#define WSUM_OFF (B_OFF + B_BYTES)
#define WSUM_BYTES ((size_t)64)
#define LT_OFF   (WSUM_OFF + WSUM_BYTES)
#define LT_BYTES ((size_t)64)
#define PSS_OFF  (LT_OFF + LT_BYTES)
#define PSS_BYTES ((size_t)256 * T_CTX * M_MOD * M_MOD * 2)
#define NEED_BIG (PSS_OFF + PSS_BYTES)

typedef __attribute__((ext_vector_type(4))) float f32x4;
typedef __attribute__((ext_vector_type(8))) _Float16 f16x8;
typedef __attribute__((ext_vector_type(2))) _Float16 h2;

union FR { uint4 u; f16x8 v; h2 h[4]; };

__device__ __forceinline__ float bf2f(unsigned short u) {
  return __uint_as_float(((unsigned int)u) << 16);
}
__device__ __forceinline__ unsigned short f2bf(float f) {
  unsigned int x = __float_as_uint(f);
  return (unsigned short)((x + 0x7fffu + ((x >> 16) & 1u)) >> 16);
}
__device__ __forceinline__ h2 cvt_pkrtz(float a, float b) {
  return __builtin_bit_cast(h2, __builtin_amdgcn_cvt_pkrtz(a, b));
}
#if __has_builtin(__builtin_amdgcn_fdot2)
__device__ __forceinline__ float fdot2f(h2 a, h2 b, float c) {
  return __builtin_amdgcn_fdot2(a, b, c, false);
}
#else
__device__ __forceinline__ float fdot2f(h2 a, h2 b, float c) {
  return c + (float)a[0] * (float)b[0] + (float)a[1] * (float)b[1];
}
#endif

#define WAITVM(N) asm volatile("s_waitcnt vmcnt(" #N ")" ::: "memory")
#define SBAR() do { __builtin_amdgcn_s_barrier(); __builtin_amdgcn_sched_barrier(0); } while (0)

// ================ zk: Z^T = (Mp @ Y^T) via f16 MFMA; also Wt ================
// 4096 blocks x 256 thr (4 waves). 64 n-rows/block, K = 128 (full D).
// Y staged f32 via gload_lds, source pre-swizzled (16B slots XOR'd by n&7).
// Mp cvt'd to f16 LDS (swizzled) once per block.
__global__ __launch_bounds__(256, 3) void zk_kernel(
    const float* __restrict__ Y, const float* __restrict__ Mp,
    const float* __restrict__ W,
    _Float16* __restrict__ Zbt, _Float16* __restrict__ Wt)
{
  __shared__ __align__(16) float    Yl[64 * 128];   // linear dest, 512B/row
  __shared__ __align__(16) _Float16 Mpl[64 * 128];  // 256B/row, 16B slots swizzled by m&7
  __shared__ float Wf[16][65];
  const int tid  = threadIdx.x;
  const int l    = tid & 63;
  const int wv   = tid >> 6;
  const int g    = l >> 4;
  const int col  = l & 15;
  const int n0   = blockIdx.x * 64;

  // --- stage Y: 32 gload_lds (8 per wave), 1KB each (2 rows) ---
#pragma unroll
  for (int k = 0; k < 8; ++k) {
    const int pr  = wv * 8 + k;            // row-pair 0..31
    const int row = pr * 2 + (l >> 5);     // n-in-tile
    const int q   = l & 31;                // 16B slot in row
    const int b   = (q & ~7) | ((q & 7) ^ (row & 7));  // global 16B block
    const float* src = Y + ((size_t)(n0 + row)) * D_OUTC + b * 4;
    __builtin_amdgcn_global_load_lds((const unsigned int*)src,
        (unsigned int*)((char*)&Yl[0] + pr * 1024), 16, 0, 0);
  }
  // --- Mp f32 -> f16 LDS (swizzled slots) ---
  {
    const int m  = tid >> 2;
    const int dq = tid & 3;
#pragma unroll
    for (int i = 0; i < 4; ++i) {
      const int s = dq * 4 + i;            // 16B f16 slot = 8 d's
      const float* mp = Mp + (size_t)m * D_OUTC + s * 8;
      float4 a = *(const float4*)mp;
      float4 b = *(const float4*)(mp + 4);
      FR o;
      o.h[0] = cvt_pkrtz(a.x, a.y); o.h[1] = cvt_pkrtz(a.z, a.w);
      o.h[2] = cvt_pkrtz(b.x, b.y); o.h[3] = cvt_pkrtz(b.z, b.w);
      const int ss = (s & ~7) | ((s & 7) ^ (m & 7));
      *(uint4*)((char*)&Mpl[0] + m * 256 + ss * 16) = o.u;
    }
  }
  // --- W slice transpose -> Wf ---
  {
    const int r  = tid >> 2;
    const int c0 = (tid & 3) * 4;
    float4 wv4 = *(const float4*)(W + (size_t)(n0 + r) * T_CTX + c0);
    Wf[c0 + 0][r] = wv4.x; Wf[c0 + 1][r] = wv4.y;
    Wf[c0 + 2][r] = wv4.z; Wf[c0 + 3][r] = wv4.w;
  }
  __syncthreads();
  // --- Wt out ---
  {
    const int t = tid >> 4, ni = tid & 15;
    h2 h0 = cvt_pkrtz(Wf[t][4 * ni], Wf[t][4 * ni + 1]);
    h2 h1 = cvt_pkrtz(Wf[t][4 * ni + 2], Wf[t][4 * ni + 3]);
    uint2 pk = {__builtin_bit_cast(unsigned int, h0), __builtin_bit_cast(unsigned int, h1)};
    *(uint2*)(Wt + (size_t)t * N_ROWS + n0 + 4 * ni) = pk;
  }
  // --- MFMA: C[m-tile qi][n-tile wv] over 4 k-steps ---
  f32x4 acc[4];
#pragma unroll
  for (int qi = 0; qi < 4; ++qi) acc[qi] = (f32x4){0.f, 0.f, 0.f, 0.f};
  const int nrow = wv * 16 + col;
#pragma unroll
  for (int ks = 0; ks < 4; ++ks) {
    // B-frag: Y[nrow][ks*32 + g*8 .. +7] from swizzled slots 2g, 2g+1
    const char* yb = (const char*)&Yl[0] + nrow * 512 + ks * 128;
    uint4 y0 = *(const uint4*)(yb + 16 * ((2 * g) ^ (nrow & 7)));
    uint4 y1 = *(const uint4*)(yb + 16 * ((2 * g + 1) ^ (nrow & 7)));
    const float* f0 = (const float*)&y0;
    const float* f1 = (const float*)&y1;
    FR B;
    B.h[0] = cvt_pkrtz(f0[0], f0[1]); B.h[1] = cvt_pkrtz(f0[2], f0[3]);
    B.h[2] = cvt_pkrtz(f1[0], f1[1]); B.h[3] = cvt_pkrtz(f1[2], f1[3]);
#pragma unroll
    for (int qi = 0; qi < 4; ++qi) {
      const int m = qi * 16 + col;
      const int s = ks * 4 + g;
      FR A;
      A.u = *(const uint4*)((char*)&Mpl[0] + m * 256 + 16 * ((s & ~7) | ((s & 7) ^ (m & 7))));
      acc[qi] = __builtin_amdgcn_mfma_f32_16x16x32_f16(A.v, B.v, acc[qi], 0, 0, 0);
    }
  }
  // --- store Z^T: m = qi*16 + g*4 + i, n = n0 + wv*16 + col ---
#pragma unroll
  for (int qi = 0; qi < 4; ++qi)
#pragma unroll
    for (int i = 0; i < 4; ++i)
      Zbt[(size_t)(qi * 16 + g * 4 + i) * N_ROWS + n0 + wv * 16 + col] =
          (_Float16)acc[qi][i];
}

// ================ ss: SS[t] = (w_t.*Z)^T Z  + B via ones-MFMA ================
// 1024 blocks (256 ns x 4 cg) x 256 thr (4 waves, wave = 1 ctx).
// 1024 n per block, 8 chunks x 128 n; 3-buffer, counted vmcnt(5), raw barriers.
#define SS_NS 256
template <bool PARTIAL>
__global__ __launch_bounds__(256, 3) void ss_kernel(
    const _Float16* __restrict__ Zbt, const _Float16* __restrict__ Wt,
    float* __restrict__ SS, float* __restrict__ Bm,
    unsigned short* __restrict__ Pss)
{
  __shared__ __align__(16) _Float16 Zl[3][64 * 128];  // 16KB each
  __shared__ __align__(16) _Float16 Wl[3][4 * 128];   // 1KB each
  const int tid = threadIdx.x;
  const int l   = tid & 63;
  const int wv  = tid >> 6;
  const int g   = l >> 4;
  const int col = l & 15;
  const int swz = (col & 7) << 4;
  const int ns  = blockIdx.x & (SS_NS - 1);
  const int cg  = blockIdx.x >> 8;
  const int ctx = cg * 4 + wv;
  const int n0b = ns * 1024;
  const int zr    = l >> 4;
  const int zslot = l & 15;

  f32x4 acc[4][4];
  f32x4 accB[4];
#pragma unroll
  for (int a = 0; a < 4; ++a) {
    accB[a] = (f32x4){0.f, 0.f, 0.f, 0.f};
#pragma unroll
    for (int b = 0; b < 4; ++b) acc[a][b] = (f32x4){0.f, 0.f, 0.f, 0.f};
  }
  FR ones;
#pragma unroll
  for (int j = 0; j < 4; ++j) ones.h[j] = (h2){(_Float16)1.f, (_Float16)1.f};

  // each wave issues exactly 5 gload_lds per chunk (uniform vmcnt accounting)
  auto stage = [&](int c, int buf) {
    const int n0 = n0b + c * 128;
#pragma unroll
    for (int i = 0; i < 4; ++i) {
      const int zm = 16 * wv + 4 * i + zr;
      const _Float16* src = Zbt + (size_t)zm * N_ROWS + n0 + 8 * (zslot ^ (zm & 7));
      __builtin_amdgcn_global_load_lds((const unsigned int*)src,
          (unsigned int*)((char*)&Zl[buf][0] + (16 * wv + 4 * i) * 256), 16, 0, 0);
    }
    const _Float16* wsrc = Wt + (size_t)(cg * 4 + zr) * N_ROWS + n0 + 8 * zslot;
    __builtin_amdgcn_global_load_lds((const unsigned int*)wsrc,
        (unsigned int*)((char*)&Wl[buf][0]), 16, 0, 0);   // 4 waves write same bytes
  };

  stage(0, 0);
  stage(1, 1);
  WAITVM(5);           // chunk 0 resident, chunk 1 in flight
  SBAR();

#pragma unroll
  for (int c = 0; c < 8; ++c) {
    const int buf = c % 3;
    if (c < 6) stage(c + 2, (c + 2) % 3);
    const char* zb = (const char*)&Zl[buf][0];
    const char* wb = (const char*)&Wl[buf][0];
#pragma unroll
    for (int s = 0; s < 4; ++s) {
      FR wfr;
      wfr.u = *(const uint4*)(wb + wv * 256 + s * 64 + g * 16);
      const int cby = ((s * 64 + g * 16) ^ swz);
      FR fr[4];
#pragma unroll
      for (int qi = 0; qi < 4; ++qi)
        fr[qi].u = *(const uint4*)(zb + (qi * 16 + col) * 256 + cby);
      __builtin_amdgcn_s_setprio(1);
#pragma unroll
      for (int qi = 0; qi < 4; ++qi) {
        FR A;
#pragma unroll
        for (int j = 0; j < 4; ++j) A.h[j] = fr[qi].h[j] * wfr.h[j];
        accB[qi] = __builtin_amdgcn_mfma_f32_16x16x32_f16(A.v, ones.v, accB[qi], 0, 0, 0);
#pragma unroll
        for (int ki = 0; ki < 4; ++ki)
          acc[qi][ki] = __builtin_amdgcn_mfma_f32_16x16x32_f16(A.v, fr[ki].v, acc[qi][ki], 0, 0, 0);
      }
      __builtin_amdgcn_s_setprio(0);
    }
    if (c < 6)      { WAITVM(5); SBAR(); }   // next chunk resident, c+2 in flight
    else if (c < 7) { WAITVM(0); SBAR(); }   // last chunk resident
  }

  // ---- B out: accB cols are duplicates; lanes col==0 hold rows g*4+i
  if (col == 0) {
#pragma unroll
    for (int qi = 0; qi < 4; ++qi)
#pragma unroll
      for (int i = 0; i < 4; ++i)
        atomicAdd(&Bm[ctx * 64 + qi * 16 + g * 4 + i], accB[qi][i]);
  }
  // ---- SS tiles out
  if (PARTIAL) {
    unsigned short* P = Pss + ((size_t)ns * 16 + ctx) * 4096;
#pragma unroll
    for (int qi = 0; qi < 4; ++qi)
#pragma unroll
      for (int ki = 0; ki < 4; ++ki)
#pragma unroll
        for (int i = 0; i < 4; ++i)
          P[(qi * 16 + g * 4 + i) * 64 + ki * 16 + col] = f2bf(acc[qi][ki][i]);
  } else {
#pragma unroll
    for (int qi = 0; qi < 4; ++qi)
#pragma unroll
      for (int ki = 0; ki < 4; ++ki)
#pragma unroll
        for (int i = 0; i < 4; ++i)
          atomicAdd(&SS[(size_t)ctx * 4096 + (qi * 16 + g * 4 + i) * 64 + ki * 16 + col],
                    acc[qi][ki][i]);
  }
}

// ================ wsum[t] = sum_n Wt[t][n] ================
__global__ __launch_bounds__(256) void wsk_kernel(const _Float16* __restrict__ Wt,
                                                  float* __restrict__ wsum)
{
  const int tid = threadIdx.x;
  const int t = blockIdx.x >> 2, q = blockIdx.x & 3;
  const uint4* base = (const uint4*)(Wt + (size_t)t * N_ROWS + q * 65536);
  const h2 one2 = {(_Float16)1.f, (_Float16)1.f};
  float s = 0.f;
  for (int i = tid; i < 8192; i += 256) {
    uint4 v = base[i];
    const h2* h = (const h2*)&v;
#pragma unroll
    for (int j = 0; j < 4; ++j) s = fdot2f(h[j], one2, s);
  }
  s += __shfl_xor(s, 1);  s += __shfl_xor(s, 2);
  s += __shfl_xor(s, 4);  s += __shfl_xor(s, 8);
  s += __shfl_xor(s, 16); s += __shfl_xor(s, 32);
  __shared__ float red[4];
  if ((tid & 63) == 0) red[tid >> 6] = s;
  __syncthreads();
  if (tid == 0) atomicAdd(&wsum[t], red[0] + red[1] + red[2] + red[3]);
}

// ================ reduce bf16 partials -> SS f32 ================
__global__ __launch_bounds__(256) void ssred_kernel(
    const unsigned short* __restrict__ Pss, float* __restrict__ SS)
{
  const int e = blockIdx.x * 256 + threadIdx.x;
  float s = 0.f;
#pragma unroll 8
  for (int b = 0; b < 256; ++b)
    s += bf2f(Pss[(size_t)b * 65536 + e]);
  SS[e] = s;
}

// ================ finalize ================
__global__ __launch_bounds__(64) void fin1_kernel(
    const float* __restrict__ SS, const float* __restrict__ Bm,
    const float* __restrict__ wsum, const float* __restrict__ Cp,
    const float* __restrict__ emaS, const unsigned char* __restrict__ inited,
    float* __restrict__ LT)
{
  const int t = blockIdx.x, m = threadIdx.x;
  __shared__ float muL[64], stdL[64];
  const float ws  = wsum[t];
  const float inv = 1.0f / ws;
  const float mu  = Bm[t * 64 + m] * inv;
  {
    float Smm = SS[(size_t)t * 4096 + m * 65] * inv - mu * mu;
    float de  = 0.9f * emaS[(size_t)t * 4096 + m * 65] + 0.1f * Smm;
    float sq  = inited[t] ? de : Smm;
    muL[m]  = mu;
    stdL[m] = sqrtf(sq + 1e-6f);
  }
  __syncthreads();
  const float sm = stdL[m];
  const float* SSr = SS + (size_t)t * 4096 + m * 64;
  const float* Cpr = Cp + (size_t)t * 4096 + m * 64;
  float acc = 0.f;
#pragma unroll
  for (int k = 0; k < 64; ++k) {
    float Sig = SSr[k] * inv - mu * muL[k];
    float den = sm * stdL[k] + 1e-6f;
    float ch  = fminf(1.f, fmaxf(-1.f, Sig / den));
    float d   = ch - Cpr[k];
    acc = fmaf(d, d, acc);
  }
#pragma unroll
  for (int o = 1; o < 64; o <<= 1) acc += __shfl_xor(acc, o);
  if (m == 0) LT[t] = acc * inv;
}

__global__ __launch_bounds__(64) void fin2_kernel(
    const float* __restrict__ LT, const float* __restrict__ wsum,
    float* __restrict__ out)
{
  const int l = threadIdx.x;
  float lt = 0.f, act = 0.f;
  if (l < 16) {
    float ws = wsum[l];
    if (ws >= 30.0f) { act = 1.f; lt = LT[l]; }
  }
#pragma unroll
  for (int o = 1; o < 16; o <<= 1) {
    lt  += __shfl_xor(lt, o);
    act += __shfl_xor(act, o);
  }
  if (l == 0) out[0] = (act > 0.f) ? (0.1f * 1.0f * lt / act) : 0.f;
}

extern "C" void kernel_launch(void* const* d_in, const int* in_sizes, int n_in,
                              void* d_out, int out_size, void* d_ws, size_t ws_size,
                              hipStream_t stream) {
  (void)in_sizes; (void)n_in; (void)out_size;
  const float* Y    = (const float*)d_in[0];
  const float* W    = (const float*)d_in[1];
  const float* Mp   = (const float*)d_in[2];
  const float* Cp   = (const float*)d_in[3];
  const float* emaS = (const float*)d_in[4];
  const unsigned char* inited = (const unsigned char*)d_in[6];
  float* out = (float*)d_out;
  char* ws = (char*)d_ws;
  _Float16* Zbt = (_Float16*)(ws + ZB_OFF);
  _Float16* Wt  = (_Float16*)(ws + WT_OFF);
  float* SS   = (float*)(ws + SS_OFF);
  float* Bm   = (float*)(ws + B_OFF);
  float* wsum = (float*)(ws + WSUM_OFF);
  float* LT   = (float*)(ws + LT_OFF);
  unsigned short* Pss = (unsigned short*)(ws + PSS_OFF);

  zk_kernel<<<N_ROWS / 64, 256, 0, stream>>>(Y, Mp, W, Zbt, Wt);
  if (ws_size >= NEED_BIG) {
    (void)hipMemsetAsync(ws + B_OFF, 0, B_BYTES + WSUM_BYTES, stream);
    ss_kernel<true><<<4 * SS_NS, 256, 0, stream>>>(Zbt, Wt, SS, Bm, Pss);
    wsk_kernel<<<64, 256, 0, stream>>>(Wt, wsum);
    ssred_kernel<<<256, 256, 0, stream>>>(Pss, SS);
  } else {
    (void)hipMemsetAsync(ws + SS_OFF, 0, SS_BYTES + B_BYTES + WSUM_BYTES, stream);
    ss_kernel<false><<<4 * SS_NS, 256, 0, stream>>>(Zbt, Wt, SS, Bm, Pss);
    wsk_kernel<<<64, 256, 0, stream>>>(Wt, wsum);
  }
  fin1_kernel<<<16, 64, 0, stream>>>(SS, Bm, wsum, Cp, emaS, inited, LT);
  fin2_kernel<<<1, 64, 0, stream>>>(LT, wsum, out);
}

// Round 7
// 138.163 us; speedup vs baseline: 7.4944x; 1.0862x over previous
//
#include <hip/hip_runtime.h>
#include <stdint.h>

#define N_ROWS 262144
#define D_OUTC 128
#define M_MOD  64
#define T_CTX  16

// ---- workspace layout (bytes) ----
#define ZB_OFF   ((size_t)0)
#define ZB_BYTES ((size_t)M_MOD * N_ROWS * 2)          // Zbt[m][n] f16  33.5MB
#define WT_OFF   (ZB_OFF + ZB_BYTES)
#define WT_BYTES ((size_t)T_CTX * N_ROWS * 2)          // Wt[t][n] f16  8.4MB
#define SS_OFF   (WT_OFF + WT_BYTES)
#define SS_BYTES ((size_t)T_CTX * M_MOD * M_MOD * 4)
#define B_OFF    (SS_OFF + SS_BYTES)
#define B_BYTES  ((size_t)T_CTX * M_MOD * 4)
#define WSUM_OFF (B_OFF + B_BYTES)
#define WSUM_BYTES ((size_t)64)
#define LT_OFF   (WSUM_OFF + WSUM_BYTES)
#define LT_BYTES ((size_t)64)
#define PSS_OFF  (LT_OFF + LT_BYTES)
#define PSS_BYTES ((size_t)256 * T_CTX * M_MOD * M_MOD * 2)
#define NEED_BIG (PSS_OFF + PSS_BYTES)

typedef __attribute__((ext_vector_type(4))) float f32x4;
typedef __attribute__((ext_vector_type(8))) _Float16 f16x8;
typedef __attribute__((ext_vector_type(2))) _Float16 h2;

union FR { uint4 u; f16x8 v; h2 h[4]; };

__device__ __forceinline__ float bf2f(unsigned short u) {
  return __uint_as_float(((unsigned int)u) << 16);
}
__device__ __forceinline__ unsigned short f2bf(float f) {
  unsigned int x = __float_as_uint(f);
  return (unsigned short)((x + 0x7fffu + ((x >> 16) & 1u)) >> 16);
}
__device__ __forceinline__ h2 cvt_pkrtz(float a, float b) {
  return __builtin_bit_cast(h2, __builtin_amdgcn_cvt_pkrtz(a, b));
}
#if __has_builtin(__builtin_amdgcn_fdot2)
__device__ __forceinline__ float fdot2f(h2 a, h2 b, float c) {
  return __builtin_amdgcn_fdot2(a, b, c, false);
}
#else
__device__ __forceinline__ float fdot2f(h2 a, h2 b, float c) {
  return c + (float)a[0] * (float)b[0] + (float)a[1] * (float)b[1];
}
#endif

#define WAITVM(N) asm volatile("s_waitcnt vmcnt(" #N ")" ::: "memory")
#define SBAR() do { __builtin_amdgcn_s_barrier(); __builtin_amdgcn_sched_barrier(0); } while (0)

// ================ zk: Z^T = (Mp @ Y^T) via f16 MFMA; also Wt ================
__global__ __launch_bounds__(256, 3) void zk_kernel(
    const float* __restrict__ Y, const float* __restrict__ Mp,
    const float* __restrict__ W,
    _Float16* __restrict__ Zbt, _Float16* __restrict__ Wt)
{
  __shared__ __align__(16) float    Yl[64 * 128];   // linear dest, 512B/row
  __shared__ __align__(16) _Float16 Mpl[64 * 128];  // 256B/row, 16B slots swizzled by m&7
  __shared__ float Wf[16][65];
  const int tid  = threadIdx.x;
  const int l    = tid & 63;
  const int wv   = tid >> 6;
  const int g    = l >> 4;
  const int col  = l & 15;
  const int n0   = blockIdx.x * 64;

#pragma unroll
  for (int k = 0; k < 8; ++k) {
    const int pr  = wv * 8 + k;
    const int row = pr * 2 + (l >> 5);
    const int q   = l & 31;
    const int b   = (q & ~7) | ((q & 7) ^ (row & 7));
    const float* src = Y + ((size_t)(n0 + row)) * D_OUTC + b * 4;
    __builtin_amdgcn_global_load_lds((const unsigned int*)src,
        (unsigned int*)((char*)&Yl[0] + pr * 1024), 16, 0, 0);
  }
  {
    const int m  = tid >> 2;
    const int dq = tid & 3;
#pragma unroll
    for (int i = 0; i < 4; ++i) {
      const int s = dq * 4 + i;
      const float* mp = Mp + (size_t)m * D_OUTC + s * 8;
      float4 a = *(const float4*)mp;
      float4 b = *(const float4*)(mp + 4);
      FR o;
      o.h[0] = cvt_pkrtz(a.x, a.y); o.h[1] = cvt_pkrtz(a.z, a.w);
      o.h[2] = cvt_pkrtz(b.x, b.y); o.h[3] = cvt_pkrtz(b.z, b.w);
      const int ss = (s & ~7) | ((s & 7) ^ (m & 7));
      *(uint4*)((char*)&Mpl[0] + m * 256 + ss * 16) = o.u;
    }
  }
  {
    const int r  = tid >> 2;
    const int c0 = (tid & 3) * 4;
    float4 wv4 = *(const float4*)(W + (size_t)(n0 + r) * T_CTX + c0);
    Wf[c0 + 0][r] = wv4.x; Wf[c0 + 1][r] = wv4.y;
    Wf[c0 + 2][r] = wv4.z; Wf[c0 + 3][r] = wv4.w;
  }
  __syncthreads();
  {
    const int t = tid >> 4, ni = tid & 15;
    h2 h0 = cvt_pkrtz(Wf[t][4 * ni], Wf[t][4 * ni + 1]);
    h2 h1 = cvt_pkrtz(Wf[t][4 * ni + 2], Wf[t][4 * ni + 3]);
    uint2 pk = {__builtin_bit_cast(unsigned int, h0), __builtin_bit_cast(unsigned int, h1)};
    *(uint2*)(Wt + (size_t)t * N_ROWS + n0 + 4 * ni) = pk;
  }
  f32x4 acc[4];
#pragma unroll
  for (int qi = 0; qi < 4; ++qi) acc[qi] = (f32x4){0.f, 0.f, 0.f, 0.f};
  const int nrow = wv * 16 + col;
#pragma unroll
  for (int ks = 0; ks < 4; ++ks) {
    const char* yb = (const char*)&Yl[0] + nrow * 512 + ks * 128;
    uint4 y0 = *(const uint4*)(yb + 16 * ((2 * g) ^ (nrow & 7)));
    uint4 y1 = *(const uint4*)(yb + 16 * ((2 * g + 1) ^ (nrow & 7)));
    const float* f0 = (const float*)&y0;
    const float* f1 = (const float*)&y1;
    FR B;
    B.h[0] = cvt_pkrtz(f0[0], f0[1]); B.h[1] = cvt_pkrtz(f0[2], f0[3]);
    B.h[2] = cvt_pkrtz(f1[0], f1[1]); B.h[3] = cvt_pkrtz(f1[2], f1[3]);
#pragma unroll
    for (int qi = 0; qi < 4; ++qi) {
      const int m = qi * 16 + col;
      const int s = ks * 4 + g;
      FR A;
      A.u = *(const uint4*)((char*)&Mpl[0] + m * 256 + 16 * ((s & ~7) | ((s & 7) ^ (m & 7))));
      acc[qi] = __builtin_amdgcn_mfma_f32_16x16x32_f16(A.v, B.v, acc[qi], 0, 0, 0);
    }
  }
#pragma unroll
  for (int qi = 0; qi < 4; ++qi)
#pragma unroll
    for (int i = 0; i < 4; ++i)
      Zbt[(size_t)(qi * 16 + g * 4 + i) * N_ROWS + n0 + wv * 16 + col] =
          (_Float16)acc[qi][i];
}

// ================ ss: SS[t] = (w_t.*Z)^T Z  (+B via ones-MFMA) ================
// 512 blocks (256 ns x 2 cg) x 512 thr (8 waves, wave = 1 ctx). 2 blocks/CU.
// 1024 n per block, 16 chunks x 64 n; NBUF=4, counted vmcnt(2), W persistent.
#define SS_NS 256
#define NCH   16
template <bool PARTIAL>
__global__ __launch_bounds__(512, 4) void ss_kernel(
    const _Float16* __restrict__ Zbt, const _Float16* __restrict__ Wt,
    float* __restrict__ SS, float* __restrict__ Bm,
    unsigned short* __restrict__ Pss)
{
  __shared__ __align__(16) _Float16 Zl[4][64 * 64];   // 8KB per buf (64 m x 128B)
  __shared__ __align__(16) _Float16 Wlds[8 * 1024];   // [wave ctx][1024 n] 16KB
  const int tid = threadIdx.x;
  const int l   = tid & 63;
  const int wv  = tid >> 6;          // 0..7
  const int g   = l >> 4;
  const int col = l & 15;
  const int ns  = blockIdx.x & (SS_NS - 1);
  const int cg  = blockIdx.x >> 8;   // 0..1
  const int ctx = cg * 8 + wv;
  const int n0b = ns * 1024;

  f32x4 acc[4][4];
  f32x4 accB[4];
#pragma unroll
  for (int a = 0; a < 4; ++a) {
    accB[a] = (f32x4){0.f, 0.f, 0.f, 0.f};
#pragma unroll
    for (int b = 0; b < 4; ++b) acc[a][b] = (f32x4){0.f, 0.f, 0.f, 0.f};
  }
  FR ones;
#pragma unroll
  for (int j = 0; j < 4; ++j) ones.h[j] = (h2){(_Float16)1.f, (_Float16)1.f};

  // --- W persistent: wave wv loads Wt[ctx][n0b..n0b+1023] (2 x 1KB) ---
#pragma unroll
  for (int k = 0; k < 2; ++k) {
    const _Float16* wsrc = Wt + (size_t)ctx * N_ROWS + n0b + k * 512 + l * 8;
    __builtin_amdgcn_global_load_lds((const unsigned int*)wsrc,
        (unsigned int*)((char*)&Wlds[0] + wv * 2048 + k * 1024), 16, 0, 0);
  }
  // --- Z staging: per chunk, wave wv stages m-rows 8wv..8wv+7 (1 x 1KB) ---
  const int zrow  = 8 * wv + (l >> 3);   // m-row this lane covers
  const int zslot = l & 7;               // 16B slot (8 n) within 64-n chunk
  auto stage = [&](int c) {
    const int n0 = n0b + c * 64;
    const _Float16* src = Zbt + (size_t)zrow * N_ROWS + n0 + 8 * (zslot ^ (zrow & 7));
    __builtin_amdgcn_global_load_lds((const unsigned int*)src,
        (unsigned int*)((char*)&Zl[c & 3][0] + wv * 1024 + l * 16), 16, 0, 0);
  };

  stage(0); stage(1); stage(2);
  WAITVM(2);           // W + chunk0 resident; chunks 1,2 in flight
  SBAR();

  for (int c = 0; c < NCH; ++c) {
    if (c + 3 < NCH) stage(c + 3);
    const char* zb = (const char*)&Zl[c & 3][0];
    const char* wb = (const char*)&Wlds[0] + wv * 2048 + c * 128;
#pragma unroll
    for (int s = 0; s < 2; ++s) {
      FR wfr;
      wfr.u = *(const uint4*)(wb + s * 64 + g * 16);
      FR fr[4];
#pragma unroll
      for (int qi = 0; qi < 4; ++qi) {
        const int r = qi * 16 + col;
        fr[qi].u = *(const uint4*)(zb + r * 128 + 16 * ((s * 4 + g) ^ (r & 7)));
      }
      __builtin_amdgcn_s_setprio(1);
#pragma unroll
      for (int qi = 0; qi < 4; ++qi) {
        FR A;
#pragma unroll
        for (int j = 0; j < 4; ++j) A.h[j] = fr[qi].h[j] * wfr.h[j];
        accB[qi] = __builtin_amdgcn_mfma_f32_16x16x32_f16(A.v, ones.v, accB[qi], 0, 0, 0);
#pragma unroll
        for (int ki = 0; ki < 4; ++ki)
          acc[qi][ki] = __builtin_amdgcn_mfma_f32_16x16x32_f16(A.v, fr[ki].v, acc[qi][ki], 0, 0, 0);
      }
      __builtin_amdgcn_s_setprio(0);
    }
    if (c + 3 < NCH)      { WAITVM(2); SBAR(); }
    else if (c == NCH - 3) { WAITVM(1); SBAR(); }
    else if (c == NCH - 2) { WAITVM(0); SBAR(); }
    // c == NCH-1: fall through
  }

  // ---- B out: lanes col==0 hold rows g*4+i of each qi tile
  if (col == 0) {
#pragma unroll
    for (int qi = 0; qi < 4; ++qi)
#pragma unroll
      for (int i = 0; i < 4; ++i)
        atomicAdd(&Bm[ctx * 64 + qi * 16 + g * 4 + i], accB[qi][i]);
  }
  // ---- SS tiles out
  if (PARTIAL) {
    unsigned short* P = Pss + ((size_t)ns * 16 + ctx) * 4096;
#pragma unroll
    for (int qi = 0; qi < 4; ++qi)
#pragma unroll
      for (int ki = 0; ki < 4; ++ki)
#pragma unroll
        for (int i = 0; i < 4; ++i)
          P[(qi * 16 + g * 4 + i) * 64 + ki * 16 + col] = f2bf(acc[qi][ki][i]);
  } else {
#pragma unroll
    for (int qi = 0; qi < 4; ++qi)
#pragma unroll
      for (int ki = 0; ki < 4; ++ki)
#pragma unroll
        for (int i = 0; i < 4; ++i)
          atomicAdd(&SS[(size_t)ctx * 4096 + (qi * 16 + g * 4 + i) * 64 + ki * 16 + col],
                    acc[qi][ki][i]);
  }
}

// ================ wsum[t] = sum_n Wt[t][n] ================
__global__ __launch_bounds__(256) void wsk_kernel(const _Float16* __restrict__ Wt,
                                                  float* __restrict__ wsum)
{
  const int tid = threadIdx.x;
  const int t = blockIdx.x >> 2, q = blockIdx.x & 3;
  const uint4* base = (const uint4*)(Wt + (size_t)t * N_ROWS + q * 65536);
  const h2 one2 = {(_Float16)1.f, (_Float16)1.f};
  float s = 0.f;
  for (int i = tid; i < 8192; i += 256) {
    uint4 v = base[i];
    const h2* h = (const h2*)&v;
#pragma unroll
    for (int j = 0; j < 4; ++j) s = fdot2f(h[j], one2, s);
  }
  s += __shfl_xor(s, 1);  s += __shfl_xor(s, 2);
  s += __shfl_xor(s, 4);  s += __shfl_xor(s, 8);
  s += __shfl_xor(s, 16); s += __shfl_xor(s, 32);
  __shared__ float red[4];
  if ((tid & 63) == 0) red[tid >> 6] = s;
  __syncthreads();
  if (tid == 0) atomicAdd(&wsum[t], red[0] + red[1] + red[2] + red[3]);
}

// ================ reduce bf16 partials -> SS f32 ================
__global__ __launch_bounds__(256) void ssred_kernel(
    const unsigned short* __restrict__ Pss, float* __restrict__ SS)
{
  const int e = blockIdx.x * 256 + threadIdx.x;
  float s = 0.f;
#pragma unroll 8
  for (int b = 0; b < 256; ++b)
    s += bf2f(Pss[(size_t)b * 65536 + e]);
  SS[e] = s;
}

// ================ finalize ================
__global__ __launch_bounds__(64) void fin1_kernel(
    const float* __restrict__ SS, const float* __restrict__ Bm,
    const float* __restrict__ wsum, const float* __restrict__ Cp,
    const float* __restrict__ emaS, const unsigned char* __restrict__ inited,
    float* __restrict__ LT)
{
  const int t = blockIdx.x, m = threadIdx.x;
  __shared__ float muL[64], stdL[64];
  const float ws  = wsum[t];
  const float inv = 1.0f / ws;
  const float mu  = Bm[t * 64 + m] * inv;
  {
    float Smm = SS[(size_t)t * 4096 + m * 65] * inv - mu * mu;
    float de  = 0.9f * emaS[(size_t)t * 4096 + m * 65] + 0.1f * Smm;
    float sq  = inited[t] ? de : Smm;
    muL[m]  = mu;
    stdL[m] = sqrtf(sq + 1e-6f);
  }
  __syncthreads();
  const float sm = stdL[m];
  const float* SSr = SS + (size_t)t * 4096 + m * 64;
  const float* Cpr = Cp + (size_t)t * 4096 + m * 64;
  float acc = 0.f;
#pragma unroll
  for (int k = 0; k < 64; ++k) {
    float Sig = SSr[k] * inv - mu * muL[k];
    float den = sm * stdL[k] + 1e-6f;
    float ch  = fminf(1.f, fmaxf(-1.f, Sig / den));
    float d   = ch - Cpr[k];
    acc = fmaf(d, d, acc);
  }
#pragma unroll
  for (int o = 1; o < 64; o <<= 1) acc += __shfl_xor(acc, o);
  if (m == 0) LT[t] = acc * inv;
}

__global__ __launch_bounds__(64) void fin2_kernel(
    const float* __restrict__ LT, const float* __restrict__ wsum,
    float* __restrict__ out)
{
  const int l = threadIdx.x;
  float lt = 0.f, act = 0.f;
  if (l < 16) {
    float ws = wsum[l];
    if (ws >= 30.0f) { act = 1.f; lt = LT[l]; }
  }
#pragma unroll
  for (int o = 1; o < 16; o <<= 1) {
    lt  += __shfl_xor(lt, o);
    act += __shfl_xor(act, o);
  }
  if (l == 0) out[0] = (act > 0.f) ? (0.1f * 1.0f * lt / act) : 0.f;
}

extern "C" void kernel_launch(void* const* d_in, const int* in_sizes, int n_in,
                              void* d_out, int out_size, void* d_ws, size_t ws_size,
                              hipStream_t stream) {
  (void)in_sizes; (void)n_in; (void)out_size;
  const float* Y    = (const float*)d_in[0];
  const float* W    = (const float*)d_in[1];
  const float* Mp   = (const float*)d_in[2];
  const float* Cp   = (const float*)d_in[3];
  const float* emaS = (const float*)d_in[4];
  const unsigned char* inited = (const unsigned char*)d_in[6];
  float* out = (float*)d_out;
  char* ws = (char*)d_ws;
  _Float16* Zbt = (_Float16*)(ws + ZB_OFF);
  _Float16* Wt  = (_Float16*)(ws + WT_OFF);
  float* SS   = (float*)(ws + SS_OFF);
  float* Bm   = (float*)(ws + B_OFF);
  float* wsum = (float*)(ws + WSUM_OFF);
  float* LT   = (float*)(ws + LT_OFF);
  unsigned short* Pss = (unsigned short*)(ws + PSS_OFF);

  zk_kernel<<<N_ROWS / 64, 256, 0, stream>>>(Y, Mp, W, Zbt, Wt);
  if (ws_size >= NEED_BIG) {
    (void)hipMemsetAsync(ws + B_OFF, 0, B_BYTES + WSUM_BYTES, stream);
    ss_kernel<true><<<2 * SS_NS, 512, 0, stream>>>(Zbt, Wt, SS, Bm, Pss);
    wsk_kernel<<<64, 256, 0, stream>>>(Wt, wsum);
    ssred_kernel<<<256, 256, 0, stream>>>(Pss, SS);
  } else {
    (void)hipMemsetAsync(ws + SS_OFF, 0, SS_BYTES + B_BYTES + WSUM_BYTES, stream);
    ss_kernel<false><<<2 * SS_NS, 512, 0, stream>>>(Zbt, Wt, SS, Bm, Pss);
    wsk_kernel<<<64, 256, 0, stream>>>(Wt, wsum);
  }
  fin1_kernel<<<16, 64, 0, stream>>>(SS, Bm, wsum, Cp, emaS, inited, LT);
  fin2_kernel<<<1, 64, 0, stream>>>(LT, wsum, out);
}